// Round 5
// baseline (424.430 us; speedup 1.0000x reference)
//
#include <hip/hip_runtime.h>
#include <cstdint>

// Zoom-aware MSA, MI355X/gfx950. Inputs fp32, output fp32.
// R9: 2-phase double-buffered global_load_lds K-loop in both GEMMs (T3-minimum):
// stage tile t+1 into the other LDS buffer right after the barrier, compute
// tile t meanwhile; ONE barrier + one (mostly pre-drained) vmcnt(0) per K-step.
// LDS 16->32KB (5 blocks/CU cap, above observed residency). Everything else
// identical to R8 (fused QKV dispatch, attn with bias reg-prefetch + exp2).

#define SQ   1024
#define HID  1024
#define CEXP 0.18033688f      // (1/sqrt(64)) * log2(e)
#define LOG2E 1.44269504f

typedef __attribute__((ext_vector_type(8))) __bf16 bf16x8;
typedef __attribute__((ext_vector_type(8))) unsigned short ushort8;
typedef __attribute__((ext_vector_type(4))) float  floatx4;

__device__ __forceinline__ float b2f(unsigned short x) {
    return __builtin_bit_cast(float, (uint32_t)x << 16);
}
__device__ __forceinline__ unsigned short f2bf(float f) {
    uint32_t u = __builtin_bit_cast(uint32_t, f);
    u += 0x7fffu + ((u >> 16) & 1u);          // RTNE
    return (unsigned short)(u >> 16);
}

// async global->LDS, 16B per lane; LDS dest = wave-uniform base + lane*16.
__device__ __forceinline__ void glds16(const void* g, void* l) {
    __builtin_amdgcn_global_load_lds(
        (const __attribute__((address_space(1))) void*)g,
        (__attribute__((address_space(3))) void*)l, 16, 0, 0);
}

// fp32 -> bf16 elementwise with scale, n % 4 == 0.
__global__ void cvt(const float* __restrict__ s, unsigned short* __restrict__ d,
                    int n4, float scale) {
    const int i = blockIdx.x * blockDim.x + threadIdx.x;
    if (i >= n4) return;
    const floatx4 v = *(const floatx4*)(s + 4 * (size_t)i);
    uint32_t lo = (uint32_t)f2bf(v[0] * scale) | ((uint32_t)f2bf(v[1] * scale) << 16);
    uint32_t hi = (uint32_t)f2bf(v[2] * scale) | ((uint32_t)f2bf(v[3] * scale) << 16);
    ((uint2*)d)[i] = make_uint2(lo, hi);
}

// 3-tensor fp32 -> bf16 (q,k,v) in one launch; blockIdx.y selects tensor.
__global__ void cvt3(const float* __restrict__ s0, const float* __restrict__ s1,
                     const float* __restrict__ s2, unsigned short* __restrict__ d0,
                     unsigned short* __restrict__ d1, unsigned short* __restrict__ d2,
                     int n4) {
    const int i = blockIdx.x * blockDim.x + threadIdx.x;
    if (i >= n4) return;
    const int z = blockIdx.y;
    const float* s = z == 0 ? s0 : (z == 1 ? s1 : s2);
    unsigned short* d = z == 0 ? d0 : (z == 1 ? d1 : d2);
    const floatx4 v = *(const floatx4*)(s + 4 * (size_t)i);
    uint32_t lo = (uint32_t)f2bf(v[0]) | ((uint32_t)f2bf(v[1]) << 16);
    uint32_t hi = (uint32_t)f2bf(v[2]) | ((uint32_t)f2bf(v[3]) << 16);
    ((uint2*)d)[i] = make_uint2(lo, hi);
}

// Fused Q/K/V projection: C_z = A_z[M,1024] @ W_z[1024,1024]^T + b_z.
// blockIdx.z picks (A,W,bias,C); z==2 (V) stores transposed
// [row>>10][n][row&1023]. 2-phase double-buffered GLDS, XCD swizzle.
__global__ __launch_bounds__(256) void gemm_qkv(
    const short* __restrict__ Aq, const short* __restrict__ Ak,
    const short* __restrict__ Av, const short* __restrict__ Wq_,
    const short* __restrict__ Wk_, const short* __restrict__ Wv_,
    const float* __restrict__ bq_, const float* __restrict__ bk_,
    const float* __restrict__ bv_, short* __restrict__ oq,
    short* __restrict__ ok, short* __restrict__ ov)
{
    __shared__ __align__(16) short As[2][4096];   // region r: rows 16r+c, k=quad*8
    __shared__ __align__(16) short Bs[2][4096];

    const int z = blockIdx.z;
    const short* A    = z == 0 ? Aq  : (z == 1 ? Ak  : Av);
    const short* Bw   = z == 0 ? Wq_ : (z == 1 ? Wk_ : Wv_);
    const float* bias = z == 0 ? bq_ : (z == 1 ? bk_ : bv_);
    short* C          = z == 0 ? oq  : (z == 1 ? ok  : ov);
    const bool trans  = (z == 2);

    const int tid = threadIdx.x;
    const int w = tid >> 6, lane = tid & 63;
    const int quad = lane >> 4, c = lane & 15;
    const int wr = w >> 1, wc = w & 1;

    // bijective XCD swizzle within the z-slice (nwg multiple of 8)
    const int nwg = gridDim.x * gridDim.y;
    const int id  = blockIdx.y * gridDim.x + blockIdx.x;
    const int nid = (id & 7) * (nwg >> 3) + (id >> 3);
    const int bn = nid & 7, bm = nid >> 3;

    const short* ag0 = A  + (size_t)(bm * 128 + w * 16 + c) * HID + quad * 8;
    const short* ag1 = ag0 + (size_t)64 * HID;
    const short* bg0 = Bw + (size_t)(bn * 128 + w * 16 + c) * HID + quad * 8;
    const short* bg1 = bg0 + (size_t)64 * HID;

    floatx4 acc[4][4] = {};

    auto stage = [&](int buf) {
        glds16(ag0, As[buf] + w * 512);
        glds16(ag1, As[buf] + (w + 4) * 512);
        glds16(bg0, Bs[buf] + w * 512);
        glds16(bg1, Bs[buf] + (w + 4) * 512);
        ag0 += 32; ag1 += 32; bg0 += 32; bg1 += 32;
    };

    stage(0);                                     // tile 0 in flight

    for (int kt = 0; kt < 32; ++kt) {
        const int cur = kt & 1;
        asm volatile("s_waitcnt vmcnt(0)" ::: "memory");   // tile kt landed
        __syncthreads();                          // all waves: tile kt visible;
                                                  // also: all reads of buf cur^1 done
        if (kt < 31) stage(cur ^ 1);              // tile kt+1 flies under the MFMAs

        bf16x8 a[4], b[4];
#pragma unroll
        for (int i = 0; i < 4; ++i)
            a[i] = *(const bf16x8*)(As[cur] + (wr * 4 + i) * 512 + lane * 8);
#pragma unroll
        for (int j = 0; j < 4; ++j)
            b[j] = *(const bf16x8*)(Bs[cur] + (wc * 4 + j) * 512 + lane * 8);
#pragma unroll
        for (int i = 0; i < 4; ++i)
#pragma unroll
            for (int j = 0; j < 4; ++j)
                acc[i][j] = __builtin_amdgcn_mfma_f32_16x16x32_bf16(a[i], b[j], acc[i][j], 0, 0, 0);
    }

    float bsv[4];
#pragma unroll
    for (int j = 0; j < 4; ++j)
        bsv[j] = bias[bn * 128 + wc * 64 + j * 16 + c];

#pragma unroll
    for (int i = 0; i < 4; ++i) {
#pragma unroll
        for (int j = 0; j < 4; ++j) {
            const int n = bn * 128 + wc * 64 + j * 16 + c;
#pragma unroll
            for (int r = 0; r < 4; ++r) {
                const int row = bm * 128 + wr * 64 + i * 16 + quad * 4 + r;  // C/D: row=quad*4+reg, col=c
                const float val = acc[i][j][r] + bsv[j];
                const size_t idx = trans
                    ? ((size_t)(row >> 10) * HID + n) * SQ + (row & 1023)
                    : (size_t)row * HID + n;
                C[idx] = (short)f2bf(val);
            }
        }
    }
}

// O-projection: C = A[M,1024] @ Bw^T + bias, fp32 out. Same 2-phase loop.
__global__ __launch_bounds__(256) void gemm_bt(
    const short* __restrict__ A, const short* __restrict__ Bw,
    const float* __restrict__ bias, float* __restrict__ C, size_t cOff)
{
    __shared__ __align__(16) short As[2][4096];
    __shared__ __align__(16) short Bs[2][4096];

    const int tid = threadIdx.x;
    const int w = tid >> 6, lane = tid & 63;
    const int quad = lane >> 4, c = lane & 15;
    const int wr = w >> 1, wc = w & 1;

    const int nwg = gridDim.x * gridDim.y;
    const int id  = blockIdx.y * gridDim.x + blockIdx.x;
    const int nid = (id & 7) * (nwg >> 3) + (id >> 3);
    const int bn = nid & 7, bm = nid >> 3;

    const short* ag0 = A  + (size_t)(bm * 128 + w * 16 + c) * HID + quad * 8;
    const short* ag1 = ag0 + (size_t)64 * HID;
    const short* bg0 = Bw + (size_t)(bn * 128 + w * 16 + c) * HID + quad * 8;
    const short* bg1 = bg0 + (size_t)64 * HID;

    floatx4 acc[4][4] = {};

    auto stage = [&](int buf) {
        glds16(ag0, As[buf] + w * 512);
        glds16(ag1, As[buf] + (w + 4) * 512);
        glds16(bg0, Bs[buf] + w * 512);
        glds16(bg1, Bs[buf] + (w + 4) * 512);
        ag0 += 32; ag1 += 32; bg0 += 32; bg1 += 32;
    };

    stage(0);

    for (int kt = 0; kt < 32; ++kt) {
        const int cur = kt & 1;
        asm volatile("s_waitcnt vmcnt(0)" ::: "memory");
        __syncthreads();
        if (kt < 31) stage(cur ^ 1);

        bf16x8 a[4], b[4];
#pragma unroll
        for (int i = 0; i < 4; ++i)
            a[i] = *(const bf16x8*)(As[cur] + (wr * 4 + i) * 512 + lane * 8);
#pragma unroll
        for (int j = 0; j < 4; ++j)
            b[j] = *(const bf16x8*)(Bs[cur] + (wc * 4 + j) * 512 + lane * 8);
#pragma unroll
        for (int i = 0; i < 4; ++i)
#pragma unroll
            for (int j = 0; j < 4; ++j)
                acc[i][j] = __builtin_amdgcn_mfma_f32_16x16x32_bf16(a[i], b[j], acc[i][j], 0, 0, 0);
    }

    float bsv[4];
#pragma unroll
    for (int j = 0; j < 4; ++j)
        bsv[j] = bias[bn * 128 + wc * 64 + j * 16 + c];

#pragma unroll
    for (int i = 0; i < 4; ++i)
#pragma unroll
        for (int j = 0; j < 4; ++j) {
            const int n = bn * 128 + wc * 64 + j * 16 + c;
#pragma unroll
            for (int r = 0; r < 4; ++r) {
                const int row = bm * 128 + wr * 64 + i * 16 + quad * 4 + r;
                C[cOff + (size_t)row * HID + n] = acc[i][j][r] + bsv[j];
            }
        }
}

// Fused attention, 64-key tiles (R8-proven). Block = 128 q-rows of (bl, h);
// wave = 32 q-rows. Score frag kb holds keys 2n+kb so each lane's score pair
// {2c,2c+1} is one b32 bf16-pair bias load / Ps write. abc & Zs pre-scaled by
// log2e -> exp2 direct. Bias dwords for tile kt+1 prefetched into registers
// during PV (hides VMEM latency; +16 VGPR).
__global__ __launch_bounds__(256) void attn(
    const short* __restrict__ qh, const short* __restrict__ kh,
    const short* __restrict__ vht, const unsigned short* __restrict__ abc,
    const float* __restrict__ zbf, short* __restrict__ aout, int b0)
{
    __shared__ __align__(16) short Kf[4096];     // region sub*4+half*2+kb
    __shared__ __align__(16) short Vf[4096];     // region sub*4+dt
    __shared__ __align__(16) short Ps[4][2304];  // per-wave 32 x 72-stride
    __shared__ float Zs[1152];

    const int tid = threadIdx.x;
    const int w = tid >> 6, lane = tid & 63;
    const int quad = lane >> 4, c = lane & 15;
    const int qb = blockIdx.x, h = blockIdx.y, bl = blockIdx.z;
    const int b = b0 + bl;

    for (int j = tid; j < 1151; j += 256)
        Zs[j] = zbf[qb * 128 + j] * LOG2E;

    const size_t blS = (size_t)bl * SQ;

    bf16x8 qa[2][2];     // A-frag: A[m=lane&15][k=quad*8+j]
#pragma unroll
    for (int m = 0; m < 2; ++m)
#pragma unroll
        for (int half = 0; half < 2; ++half)
            qa[m][half] = *(const bf16x8*)(qh + (blS + qb * 128 + w * 32 + m * 16 + c) * HID
                                               + h * 64 + half * 32 + quad * 8);

    // wave w stages: K regions (sub,half=w>>1,kb=w&1), V regions (sub,dt=w)
    const short* kg = kh  + (blS + 2 * c + (w & 1)) * HID + h * 64 + (w >> 1) * 32 + quad * 8;
    const short* vg = vht + ((size_t)bl * HID + h * 64 + w * 16 + c) * SQ + quad * 8;
    const size_t bge = ((size_t)b * SQ + qb * 128 + w * 32 + quad * 4) * SQ;

    bf16x8 kv0 = *(const bf16x8*)kg, kv1 = *(const bf16x8*)(kg + 32 * HID);
    bf16x8 vv0 = *(const bf16x8*)vg, vv1 = *(const bf16x8*)(vg + 32);

    uint32_t bp[2][4][2];
    auto loadB = [&](int K0) {
#pragma unroll
        for (int m = 0; m < 2; ++m)
#pragma unroll
            for (int r = 0; r < 4; ++r)
#pragma unroll
                for (int sub = 0; sub < 2; ++sub)
                    bp[m][r][sub] = *(const uint32_t*)(abc + bge + (size_t)(m * 16 + r) * SQ
                                                        + K0 + sub * 32 + 2 * c);
    };
    loadB(0);

    floatx4 o[2][4] = {};
    float sume[2][4] = {};

    for (int kt = 0; kt < 16; ++kt) {
        __syncthreads();
        *(bf16x8*)(Kf + w * 512 + lane * 8)       = kv0;
        *(bf16x8*)(Kf + (w + 4) * 512 + lane * 8) = kv1;
        *(bf16x8*)(Vf + w * 512 + lane * 8)       = vv0;
        *(bf16x8*)(Vf + (w + 4) * 512 + lane * 8) = vv1;
        __syncthreads();

        if (kt < 15) {                            // prefetch next 64-key tile
            kg += 64 * HID; vg += 64;
            kv0 = *(const bf16x8*)kg; kv1 = *(const bf16x8*)(kg + 32 * HID);
            vv0 = *(const bf16x8*)vg; vv1 = *(const bf16x8*)(vg + 32);
        }

        floatx4 sc[2][2][2] = {};                 // [m][sub][kb]
#pragma unroll
        for (int sub = 0; sub < 2; ++sub) {
            bf16x8 kf[2][2];
#pragma unroll
            for (int half = 0; half < 2; ++half)
#pragma unroll
                for (int kb = 0; kb < 2; ++kb)
                    kf[half][kb] = *(const bf16x8*)(Kf + (sub * 4 + half * 2 + kb) * 512 + lane * 8);
#pragma unroll
            for (int m = 0; m < 2; ++m)
#pragma unroll
                for (int kb = 0; kb < 2; ++kb) {
                    sc[m][sub][kb] = __builtin_amdgcn_mfma_f32_16x16x32_bf16(qa[m][0], kf[0][kb], sc[m][sub][kb], 0, 0, 0);
                    sc[m][sub][kb] = __builtin_amdgcn_mfma_f32_16x16x32_bf16(qa[m][1], kf[1][kb], sc[m][sub][kb], 0, 0, 0);
                }
        }

        const int k0 = kt * 64;
#pragma unroll
        for (int m = 0; m < 2; ++m) {
#pragma unroll
            for (int r = 0; r < 4; ++r) {
                const int lrq = w * 32 + m * 16 + quad * 4 + r;
                const int tb = lrq + 1023 - k0;                   // Zs idx = tb - local key
#pragma unroll
                for (int sub = 0; sub < 2; ++sub) {
                    const int kl = sub * 32 + 2 * c;
                    const uint32_t bv_ = bp[m][r][sub];
                    const float z0 = Zs[tb - kl], z1 = Zs[tb - kl - 1];
                    const float s0 = sc[m][sub][0][r] * CEXP + z0 + b2f((unsigned short)(bv_ & 0xffffu));
                    const float s1 = sc[m][sub][1][r] * CEXP + z1
                                   + __builtin_bit_cast(float, bv_ & 0xffff0000u);
                    const float e0 = __builtin_amdgcn_exp2f(s0);
                    const float e1 = __builtin_amdgcn_exp2f(s1);
                    sume[m][r] += e0 + e1;
                    const uint32_t pp = (uint32_t)f2bf(e0) | ((uint32_t)f2bf(e1) << 16);
                    *(uint32_t*)(&Ps[w][0] + (m * 16 + quad * 4 + r) * 72 + kl) = pp;
                }
            }
        }

        if (kt < 15) loadB(k0 + 64);              // hide bias latency under PV

#pragma unroll
        for (int sub = 0; sub < 2; ++sub) {
            bf16x8 ap[2];
#pragma unroll
            for (int m = 0; m < 2; ++m)
                ap[m] = *(const bf16x8*)(&Ps[w][0] + (m * 16 + c) * 72 + sub * 32 + quad * 8);
#pragma unroll
            for (int dt = 0; dt < 4; ++dt) {
                const bf16x8 vf = *(const bf16x8*)(Vf + (sub * 4 + dt) * 512 + lane * 8);
#pragma unroll
                for (int m = 0; m < 2; ++m)
                    o[m][dt] = __builtin_amdgcn_mfma_f32_16x16x32_bf16(ap[m], vf, o[m][dt], 0, 0, 0);
            }
        }
    }

#pragma unroll
    for (int m = 0; m < 2; ++m)
#pragma unroll
        for (int r = 0; r < 4; ++r) {
            float s = sume[m][r];
            s += __shfl_xor(s, 1);
            s += __shfl_xor(s, 2);
            s += __shfl_xor(s, 4);
            s += __shfl_xor(s, 8);
            sume[m][r] = 1.0f / s;
        }

#pragma unroll
    for (int m = 0; m < 2; ++m)
#pragma unroll
        for (int dt = 0; dt < 4; ++dt)
#pragma unroll
            for (int r = 0; r < 4; ++r) {
                const size_t row = blS + qb * 128 + w * 32 + m * 16 + quad * 4 + r;
                ((unsigned short*)aout)[row * HID + h * 64 + dt * 16 + c] =
                    f2bf(o[m][dt][r] * sume[m][r]);
            }
}

extern "C" void kernel_launch(void* const* d_in, const int* in_sizes, int n_in,
                              void* d_out, int out_size, void* d_ws, size_t ws_size,
                              hipStream_t stream) {
    const float* q  = (const float*)d_in[0];
    const float* k  = (const float*)d_in[1];
    const float* v  = (const float*)d_in[2];
    const float* ab = (const float*)d_in[3];
    const float* Wq = (const float*)d_in[4];  const float* bq = (const float*)d_in[5];
    const float* Wk = (const float*)d_in[6];  const float* bk = (const float*)d_in[7];
    const float* Wv = (const float*)d_in[8];  const float* bv = (const float*)d_in[9];
    const float* Wo = (const float*)d_in[10]; const float* bo = (const float*)d_in[11];
    const float* zb = (const float*)d_in[12];

    const size_t perB = (size_t)SQ * HID;            // 1M elems per batch
    const size_t WN   = (size_t)HID * HID;           // 1M elems per weight

    // ws: 4 bf16 weights (8MB) + bf16 attn_bias (16MB) + 6 x G x 2MB
    // (cbq,cbk,cbv, qh,khp,vht; ao aliases cbq).
    int G = 8;
    while (G > 1 && 24ull * 1024 * 1024 + 12ull * G * perB > ws_size) G >>= 1;

    unsigned short* Wqc = (unsigned short*)d_ws;
    unsigned short* Wkc = Wqc + WN;
    unsigned short* Wvc = Wkc + WN;
    unsigned short* Woc = Wvc + WN;
    unsigned short* abc = Woc + WN;                  // 8M elems (all batches)
    short* cbq = (short*)(abc + 8 * perB);           // bf16 A staging (q,k,v)
    short* cbk = cbq + (size_t)G * perB;
    short* cbv = cbk + (size_t)G * perB;
    short* qh  = cbv + (size_t)G * perB;
    short* khp = qh  + (size_t)G * perB;
    short* vht = khp + (size_t)G * perB;
    short* ao  = cbq;                                // alias: cb* dead after QKV

    const dim3 bt(256);
    const int ngroups = 8 / G;
    const int cn4 = (int)(G * perB / 4);
    const int cgrid = (cn4 + 255) / 256;

    cvt<<<(WN / 4 + 255) / 256, 256, 0, stream>>>(Wq, Wqc, WN / 4, 1.0f);
    cvt<<<(WN / 4 + 255) / 256, 256, 0, stream>>>(Wk, Wkc, WN / 4, 1.0f);
    cvt<<<(WN / 4 + 255) / 256, 256, 0, stream>>>(Wv, Wvc, WN / 4, 1.0f);
    cvt<<<(WN / 4 + 255) / 256, 256, 0, stream>>>(Wo, Woc, WN / 4, 1.0f);
    cvt<<<(8 * perB / 4 + 255) / 256, 256, 0, stream>>>(ab, abc, 8 * perB / 4, LOG2E);

    for (int g = 0; g < ngroups; ++g) {
        const size_t off = (size_t)g * G * perB;
        cvt3<<<dim3(cgrid, 3), 256, 0, stream>>>(
            q + off, k + off, v + off,
            (unsigned short*)cbq, (unsigned short*)cbk, (unsigned short*)cbv, cn4);
        gemm_qkv<<<dim3(8, G * 8, 3), bt, 0, stream>>>(
            cbq, cbk, cbv, (short*)Wqc, (short*)Wkc, (short*)Wvc,
            bq, bk, bv, qh, khp, vht);
        attn<<<dim3(8, 16, G), bt, 0, stream>>>(qh, khp, vht, abc, zb, ao, g * G);
        gemm_bt<<<dim3(8, G * 8), bt, 0, stream>>>(ao, (short*)Woc, bo, (float*)d_out, off);
    }
}

// Round 7
// 420.093 us; speedup vs baseline: 1.0103x; 1.0103x over previous
//
#include <hip/hip_runtime.h>
#include <cstdint>

// Zoom-aware MSA, MI355X/gfx950. Inputs fp32, output fp32.
// R11 (= R10 + hardened barrier): counted-vmcnt TRIPLE-buffered GLDS K-loop
// in both GEMMs (T4): two tiles in flight, s_waitcnt vmcnt(4) (never 0
// in-loop); per step: sched_barrier + lgkmcnt(0) drain + s_barrier +
// sched_barrier (closes the theoretical ds_read-vs-DMA race of raw s_barrier).
// LDS 48KB. Fused QKV dispatch, attn with bias reg-prefetch + exp2 (R8-proven).

#define SQ   1024
#define HID  1024
#define CEXP 0.18033688f      // (1/sqrt(64)) * log2(e)
#define LOG2E 1.44269504f

typedef __attribute__((ext_vector_type(8))) __bf16 bf16x8;
typedef __attribute__((ext_vector_type(8))) unsigned short ushort8;
typedef __attribute__((ext_vector_type(4))) float  floatx4;

__device__ __forceinline__ float b2f(unsigned short x) {
    return __builtin_bit_cast(float, (uint32_t)x << 16);
}
__device__ __forceinline__ unsigned short f2bf(float f) {
    uint32_t u = __builtin_bit_cast(uint32_t, f);
    u += 0x7fffu + ((u >> 16) & 1u);          // RTNE
    return (unsigned short)(u >> 16);
}

// async global->LDS, 16B per lane; LDS dest = wave-uniform base + lane*16.
__device__ __forceinline__ void glds16(const void* g, void* l) {
    __builtin_amdgcn_global_load_lds(
        (const __attribute__((address_space(1))) void*)g,
        (__attribute__((address_space(3))) void*)l, 16, 0, 0);
}

// pipeline barrier: tile-kt visible, prior reads drained, no cross-motion.
__device__ __forceinline__ void pipe_barrier(int vm) {
    __builtin_amdgcn_sched_barrier(0);
    if (vm == 4) asm volatile("s_waitcnt vmcnt(4) lgkmcnt(0)" ::: "memory");
    else         asm volatile("s_waitcnt vmcnt(0) lgkmcnt(0)" ::: "memory");
    __builtin_amdgcn_s_barrier();
    __builtin_amdgcn_sched_barrier(0);
}

// fp32 -> bf16 elementwise with scale, n % 4 == 0.
__global__ void cvt(const float* __restrict__ s, unsigned short* __restrict__ d,
                    int n4, float scale) {
    const int i = blockIdx.x * blockDim.x + threadIdx.x;
    if (i >= n4) return;
    const floatx4 v = *(const floatx4*)(s + 4 * (size_t)i);
    uint32_t lo = (uint32_t)f2bf(v[0] * scale) | ((uint32_t)f2bf(v[1] * scale) << 16);
    uint32_t hi = (uint32_t)f2bf(v[2] * scale) | ((uint32_t)f2bf(v[3] * scale) << 16);
    ((uint2*)d)[i] = make_uint2(lo, hi);
}

// 3-tensor fp32 -> bf16 (q,k,v) in one launch; blockIdx.y selects tensor.
__global__ void cvt3(const float* __restrict__ s0, const float* __restrict__ s1,
                     const float* __restrict__ s2, unsigned short* __restrict__ d0,
                     unsigned short* __restrict__ d1, unsigned short* __restrict__ d2,
                     int n4) {
    const int i = blockIdx.x * blockDim.x + threadIdx.x;
    if (i >= n4) return;
    const int z = blockIdx.y;
    const float* s = z == 0 ? s0 : (z == 1 ? s1 : s2);
    unsigned short* d = z == 0 ? d0 : (z == 1 ? d1 : d2);
    const floatx4 v = *(const floatx4*)(s + 4 * (size_t)i);
    uint32_t lo = (uint32_t)f2bf(v[0]) | ((uint32_t)f2bf(v[1]) << 16);
    uint32_t hi = (uint32_t)f2bf(v[2]) | ((uint32_t)f2bf(v[3]) << 16);
    ((uint2*)d)[i] = make_uint2(lo, hi);
}

// Fused Q/K/V projection: C_z = A_z[M,1024] @ W_z[1024,1024]^T + b_z.
// blockIdx.z picks (A,W,bias,C); z==2 (V) stores transposed
// [row>>10][n][row&1023]. 3-buffer counted-vmcnt GLDS pipeline, XCD swizzle.
__global__ __launch_bounds__(256) void gemm_qkv(
    const short* __restrict__ Aq, const short* __restrict__ Ak,
    const short* __restrict__ Av, const short* __restrict__ Wq_,
    const short* __restrict__ Wk_, const short* __restrict__ Wv_,
    const float* __restrict__ bq_, const float* __restrict__ bk_,
    const float* __restrict__ bv_, short* __restrict__ oq,
    short* __restrict__ ok, short* __restrict__ ov)
{
    __shared__ __align__(16) short As[3][4096];   // region r: rows 16r+c, k=quad*8
    __shared__ __align__(16) short Bs[3][4096];

    const int z = blockIdx.z;
    const short* A    = z == 0 ? Aq  : (z == 1 ? Ak  : Av);
    const short* Bw   = z == 0 ? Wq_ : (z == 1 ? Wk_ : Wv_);
    const float* bias = z == 0 ? bq_ : (z == 1 ? bk_ : bv_);
    short* C          = z == 0 ? oq  : (z == 1 ? ok  : ov);
    const bool trans  = (z == 2);

    const int tid = threadIdx.x;
    const int w = tid >> 6, lane = tid & 63;
    const int quad = lane >> 4, c = lane & 15;
    const int wr = w >> 1, wc = w & 1;

    // bijective XCD swizzle within the z-slice (nwg multiple of 8)
    const int nwg = gridDim.x * gridDim.y;
    const int id  = blockIdx.y * gridDim.x + blockIdx.x;
    const int nid = (id & 7) * (nwg >> 3) + (id >> 3);
    const int bn = nid & 7, bm = nid >> 3;

    const short* ag0 = A  + (size_t)(bm * 128 + w * 16 + c) * HID + quad * 8;
    const short* ag1 = ag0 + (size_t)64 * HID;
    const short* bg0 = Bw + (size_t)(bn * 128 + w * 16 + c) * HID + quad * 8;
    const short* bg1 = bg0 + (size_t)64 * HID;

    floatx4 acc[4][4] = {};

    auto stage = [&](int buf) {
        glds16(ag0, As[buf] + w * 512);
        glds16(ag1, As[buf] + (w + 4) * 512);
        glds16(bg0, Bs[buf] + w * 512);
        glds16(bg1, Bs[buf] + (w + 4) * 512);
        ag0 += 32; ag1 += 32; bg0 += 32; bg1 += 32;
    };

    stage(0); stage(1);                           // tiles 0,1 in flight

    for (int kt = 0; kt < 32; ++kt) {
        pipe_barrier(kt < 31 ? 4 : 0);            // tile kt landed & visible
        if (kt < 30) stage((kt + 2) % 3);         // keep 2 tiles in flight

        const short* Ac = As[kt % 3];
        const short* Bc = Bs[kt % 3];
        bf16x8 a[4], b[4];
#pragma unroll
        for (int i = 0; i < 4; ++i)
            a[i] = *(const bf16x8*)(Ac + (wr * 4 + i) * 512 + lane * 8);
#pragma unroll
        for (int j = 0; j < 4; ++j)
            b[j] = *(const bf16x8*)(Bc + (wc * 4 + j) * 512 + lane * 8);
#pragma unroll
        for (int i = 0; i < 4; ++i)
#pragma unroll
            for (int j = 0; j < 4; ++j)
                acc[i][j] = __builtin_amdgcn_mfma_f32_16x16x32_bf16(a[i], b[j], acc[i][j], 0, 0, 0);
    }

    float bsv[4];
#pragma unroll
    for (int j = 0; j < 4; ++j)
        bsv[j] = bias[bn * 128 + wc * 64 + j * 16 + c];

#pragma unroll
    for (int i = 0; i < 4; ++i) {
#pragma unroll
        for (int j = 0; j < 4; ++j) {
            const int n = bn * 128 + wc * 64 + j * 16 + c;
#pragma unroll
            for (int r = 0; r < 4; ++r) {
                const int row = bm * 128 + wr * 64 + i * 16 + quad * 4 + r;  // C/D: row=quad*4+reg, col=c
                const float val = acc[i][j][r] + bsv[j];
                const size_t idx = trans
                    ? ((size_t)(row >> 10) * HID + n) * SQ + (row & 1023)
                    : (size_t)row * HID + n;
                C[idx] = (short)f2bf(val);
            }
        }
    }
}

// O-projection: C = A[M,1024] @ Bw^T + bias, fp32 out. Same 3-buffer pipeline.
__global__ __launch_bounds__(256) void gemm_bt(
    const short* __restrict__ A, const short* __restrict__ Bw,
    const float* __restrict__ bias, float* __restrict__ C, size_t cOff)
{
    __shared__ __align__(16) short As[3][4096];
    __shared__ __align__(16) short Bs[3][4096];

    const int tid = threadIdx.x;
    const int w = tid >> 6, lane = tid & 63;
    const int quad = lane >> 4, c = lane & 15;
    const int wr = w >> 1, wc = w & 1;

    const int nwg = gridDim.x * gridDim.y;
    const int id  = blockIdx.y * gridDim.x + blockIdx.x;
    const int nid = (id & 7) * (nwg >> 3) + (id >> 3);
    const int bn = nid & 7, bm = nid >> 3;

    const short* ag0 = A  + (size_t)(bm * 128 + w * 16 + c) * HID + quad * 8;
    const short* ag1 = ag0 + (size_t)64 * HID;
    const short* bg0 = Bw + (size_t)(bn * 128 + w * 16 + c) * HID + quad * 8;
    const short* bg1 = bg0 + (size_t)64 * HID;

    floatx4 acc[4][4] = {};

    auto stage = [&](int buf) {
        glds16(ag0, As[buf] + w * 512);
        glds16(ag1, As[buf] + (w + 4) * 512);
        glds16(bg0, Bs[buf] + w * 512);
        glds16(bg1, Bs[buf] + (w + 4) * 512);
        ag0 += 32; ag1 += 32; bg0 += 32; bg1 += 32;
    };

    stage(0); stage(1);

    for (int kt = 0; kt < 32; ++kt) {
        pipe_barrier(kt < 31 ? 4 : 0);
        if (kt < 30) stage((kt + 2) % 3);

        const short* Ac = As[kt % 3];
        const short* Bc = Bs[kt % 3];
        bf16x8 a[4], b[4];
#pragma unroll
        for (int i = 0; i < 4; ++i)
            a[i] = *(const bf16x8*)(Ac + (wr * 4 + i) * 512 + lane * 8);
#pragma unroll
        for (int j = 0; j < 4; ++j)
            b[j] = *(const bf16x8*)(Bc + (wc * 4 + j) * 512 + lane * 8);
#pragma unroll
        for (int i = 0; i < 4; ++i)
#pragma unroll
            for (int j = 0; j < 4; ++j)
                acc[i][j] = __builtin_amdgcn_mfma_f32_16x16x32_bf16(a[i], b[j], acc[i][j], 0, 0, 0);
    }

    float bsv[4];
#pragma unroll
    for (int j = 0; j < 4; ++j)
        bsv[j] = bias[bn * 128 + wc * 64 + j * 16 + c];

#pragma unroll
    for (int i = 0; i < 4; ++i)
#pragma unroll
        for (int j = 0; j < 4; ++j) {
            const int n = bn * 128 + wc * 64 + j * 16 + c;
#pragma unroll
            for (int r = 0; r < 4; ++r) {
                const int row = bm * 128 + wr * 64 + i * 16 + quad * 4 + r;
                C[cOff + (size_t)row * HID + n] = acc[i][j][r] + bsv[j];
            }
        }
}

// Fused attention, 64-key tiles (R8-proven). Block = 128 q-rows of (bl, h);
// wave = 32 q-rows. Score frag kb holds keys 2n+kb so each lane's score pair
// {2c,2c+1} is one b32 bf16-pair bias load / Ps write. abc & Zs pre-scaled by
// log2e -> exp2 direct. Bias dwords for tile kt+1 prefetched into registers
// during PV (hides VMEM latency; +16 VGPR).
__global__ __launch_bounds__(256) void attn(
    const short* __restrict__ qh, const short* __restrict__ kh,
    const short* __restrict__ vht, const unsigned short* __restrict__ abc,
    const float* __restrict__ zbf, short* __restrict__ aout, int b0)
{
    __shared__ __align__(16) short Kf[4096];     // region sub*4+half*2+kb
    __shared__ __align__(16) short Vf[4096];     // region sub*4+dt
    __shared__ __align__(16) short Ps[4][2304];  // per-wave 32 x 72-stride
    __shared__ float Zs[1152];

    const int tid = threadIdx.x;
    const int w = tid >> 6, lane = tid & 63;
    const int quad = lane >> 4, c = lane & 15;
    const int qb = blockIdx.x, h = blockIdx.y, bl = blockIdx.z;
    const int b = b0 + bl;

    for (int j = tid; j < 1151; j += 256)
        Zs[j] = zbf[qb * 128 + j] * LOG2E;

    const size_t blS = (size_t)bl * SQ;

    bf16x8 qa[2][2];     // A-frag: A[m=lane&15][k=quad*8+j]
#pragma unroll
    for (int m = 0; m < 2; ++m)
#pragma unroll
        for (int half = 0; half < 2; ++half)
            qa[m][half] = *(const bf16x8*)(qh + (blS + qb * 128 + w * 32 + m * 16 + c) * HID
                                               + h * 64 + half * 32 + quad * 8);

    // wave w stages: K regions (sub,half=w>>1,kb=w&1), V regions (sub,dt=w)
    const short* kg = kh  + (blS + 2 * c + (w & 1)) * HID + h * 64 + (w >> 1) * 32 + quad * 8;
    const short* vg = vht + ((size_t)bl * HID + h * 64 + w * 16 + c) * SQ + quad * 8;
    const size_t bge = ((size_t)b * SQ + qb * 128 + w * 32 + quad * 4) * SQ;

    bf16x8 kv0 = *(const bf16x8*)kg, kv1 = *(const bf16x8*)(kg + 32 * HID);
    bf16x8 vv0 = *(const bf16x8*)vg, vv1 = *(const bf16x8*)(vg + 32);

    uint32_t bp[2][4][2];
    auto loadB = [&](int K0) {
#pragma unroll
        for (int m = 0; m < 2; ++m)
#pragma unroll
            for (int r = 0; r < 4; ++r)
#pragma unroll
                for (int sub = 0; sub < 2; ++sub)
                    bp[m][r][sub] = *(const uint32_t*)(abc + bge + (size_t)(m * 16 + r) * SQ
                                                        + K0 + sub * 32 + 2 * c);
    };
    loadB(0);

    floatx4 o[2][4] = {};
    float sume[2][4] = {};

    for (int kt = 0; kt < 16; ++kt) {
        __syncthreads();
        *(bf16x8*)(Kf + w * 512 + lane * 8)       = kv0;
        *(bf16x8*)(Kf + (w + 4) * 512 + lane * 8) = kv1;
        *(bf16x8*)(Vf + w * 512 + lane * 8)       = vv0;
        *(bf16x8*)(Vf + (w + 4) * 512 + lane * 8) = vv1;
        __syncthreads();

        if (kt < 15) {                            // prefetch next 64-key tile
            kg += 64 * HID; vg += 64;
            kv0 = *(const bf16x8*)kg; kv1 = *(const bf16x8*)(kg + 32 * HID);
            vv0 = *(const bf16x8*)vg; vv1 = *(const bf16x8*)(vg + 32);
        }

        floatx4 sc[2][2][2] = {};                 // [m][sub][kb]
#pragma unroll
        for (int sub = 0; sub < 2; ++sub) {
            bf16x8 kf[2][2];
#pragma unroll
            for (int half = 0; half < 2; ++half)
#pragma unroll
                for (int kb = 0; kb < 2; ++kb)
                    kf[half][kb] = *(const bf16x8*)(Kf + (sub * 4 + half * 2 + kb) * 512 + lane * 8);
#pragma unroll
            for (int m = 0; m < 2; ++m)
#pragma unroll
                for (int kb = 0; kb < 2; ++kb) {
                    sc[m][sub][kb] = __builtin_amdgcn_mfma_f32_16x16x32_bf16(qa[m][0], kf[0][kb], sc[m][sub][kb], 0, 0, 0);
                    sc[m][sub][kb] = __builtin_amdgcn_mfma_f32_16x16x32_bf16(qa[m][1], kf[1][kb], sc[m][sub][kb], 0, 0, 0);
                }
        }

        const int k0 = kt * 64;
#pragma unroll
        for (int m = 0; m < 2; ++m) {
#pragma unroll
            for (int r = 0; r < 4; ++r) {
                const int lrq = w * 32 + m * 16 + quad * 4 + r;
                const int tb = lrq + 1023 - k0;                   // Zs idx = tb - local key
#pragma unroll
                for (int sub = 0; sub < 2; ++sub) {
                    const int kl = sub * 32 + 2 * c;
                    const uint32_t bv_ = bp[m][r][sub];
                    const float z0 = Zs[tb - kl], z1 = Zs[tb - kl - 1];
                    const float s0 = sc[m][sub][0][r] * CEXP + z0 + b2f((unsigned short)(bv_ & 0xffffu));
                    const float s1 = sc[m][sub][1][r] * CEXP + z1
                                   + __builtin_bit_cast(float, bv_ & 0xffff0000u);
                    const float e0 = __builtin_amdgcn_exp2f(s0);
                    const float e1 = __builtin_amdgcn_exp2f(s1);
                    sume[m][r] += e0 + e1;
                    const uint32_t pp = (uint32_t)f2bf(e0) | ((uint32_t)f2bf(e1) << 16);
                    *(uint32_t*)(&Ps[w][0] + (m * 16 + quad * 4 + r) * 72 + kl) = pp;
                }
            }
        }

        if (kt < 15) loadB(k0 + 64);              // hide bias latency under PV

#pragma unroll
        for (int sub = 0; sub < 2; ++sub) {
            bf16x8 ap[2];
#pragma unroll
            for (int m = 0; m < 2; ++m)
                ap[m] = *(const bf16x8*)(&Ps[w][0] + (m * 16 + c) * 72 + sub * 32 + quad * 8);
#pragma unroll
            for (int dt = 0; dt < 4; ++dt) {
                const bf16x8 vf = *(const bf16x8*)(Vf + (sub * 4 + dt) * 512 + lane * 8);
#pragma unroll
                for (int m = 0; m < 2; ++m)
                    o[m][dt] = __builtin_amdgcn_mfma_f32_16x16x32_bf16(ap[m], vf, o[m][dt], 0, 0, 0);
            }
        }
    }

#pragma unroll
    for (int m = 0; m < 2; ++m)
#pragma unroll
        for (int r = 0; r < 4; ++r) {
            float s = sume[m][r];
            s += __shfl_xor(s, 1);
            s += __shfl_xor(s, 2);
            s += __shfl_xor(s, 4);
            s += __shfl_xor(s, 8);
            sume[m][r] = 1.0f / s;
        }

#pragma unroll
    for (int m = 0; m < 2; ++m)
#pragma unroll
        for (int dt = 0; dt < 4; ++dt)
#pragma unroll
            for (int r = 0; r < 4; ++r) {
                const size_t row = blS + qb * 128 + w * 32 + m * 16 + quad * 4 + r;
                ((unsigned short*)aout)[row * HID + h * 64 + dt * 16 + c] =
                    f2bf(o[m][dt][r] * sume[m][r]);
            }
}

extern "C" void kernel_launch(void* const* d_in, const int* in_sizes, int n_in,
                              void* d_out, int out_size, void* d_ws, size_t ws_size,
                              hipStream_t stream) {
    const float* q  = (const float*)d_in[0];
    const float* k  = (const float*)d_in[1];
    const float* v  = (const float*)d_in[2];
    const float* ab = (const float*)d_in[3];
    const float* Wq = (const float*)d_in[4];  const float* bq = (const float*)d_in[5];
    const float* Wk = (const float*)d_in[6];  const float* bk = (const float*)d_in[7];
    const float* Wv = (const float*)d_in[8];  const float* bv = (const float*)d_in[9];
    const float* Wo = (const float*)d_in[10]; const float* bo = (const float*)d_in[11];
    const float* zb = (const float*)d_in[12];

    const size_t perB = (size_t)SQ * HID;            // 1M elems per batch
    const size_t WN   = (size_t)HID * HID;           // 1M elems per weight

    // ws: 4 bf16 weights (8MB) + bf16 attn_bias (16MB) + 6 x G x 2MB
    // (cbq,cbk,cbv, qh,khp,vht; ao aliases cbq).
    int G = 8;
    while (G > 1 && 24ull * 1024 * 1024 + 12ull * G * perB > ws_size) G >>= 1;

    unsigned short* Wqc = (unsigned short*)d_ws;
    unsigned short* Wkc = Wqc + WN;
    unsigned short* Wvc = Wkc + WN;
    unsigned short* Woc = Wvc + WN;
    unsigned short* abc = Woc + WN;                  // 8M elems (all batches)
    short* cbq = (short*)(abc + 8 * perB);           // bf16 A staging (q,k,v)
    short* cbk = cbq + (size_t)G * perB;
    short* cbv = cbk + (size_t)G * perB;
    short* qh  = cbv + (size_t)G * perB;
    short* khp = qh  + (size_t)G * perB;
    short* vht = khp + (size_t)G * perB;
    short* ao  = cbq;                                // alias: cb* dead after QKV

    const dim3 bt(256);
    const int ngroups = 8 / G;
    const int cn4 = (int)(G * perB / 4);
    const int cgrid = (cn4 + 255) / 256;

    cvt<<<(WN / 4 + 255) / 256, 256, 0, stream>>>(Wq, Wqc, WN / 4, 1.0f);
    cvt<<<(WN / 4 + 255) / 256, 256, 0, stream>>>(Wk, Wkc, WN / 4, 1.0f);
    cvt<<<(WN / 4 + 255) / 256, 256, 0, stream>>>(Wv, Wvc, WN / 4, 1.0f);
    cvt<<<(WN / 4 + 255) / 256, 256, 0, stream>>>(Wo, Woc, WN / 4, 1.0f);
    cvt<<<(8 * perB / 4 + 255) / 256, 256, 0, stream>>>(ab, abc, 8 * perB / 4, LOG2E);

    for (int g = 0; g < ngroups; ++g) {
        const size_t off = (size_t)g * G * perB;
        cvt3<<<dim3(cgrid, 3), 256, 0, stream>>>(
            q + off, k + off, v + off,
            (unsigned short*)cbq, (unsigned short*)cbk, (unsigned short*)cbv, cn4);
        gemm_qkv<<<dim3(8, G * 8, 3), bt, 0, stream>>>(
            cbq, cbk, cbv, (short*)Wqc, (short*)Wkc, (short*)Wvc,
            bq, bk, bv, qh, khp, vht);
        attn<<<dim3(8, 16, G), bt, 0, stream>>>(qh, khp, vht, abc, zb, ao, g * G);
        gemm_bt<<<dim3(8, G * 8), bt, 0, stream>>>(ao, (short*)Woc, bo, (float*)d_out, off);
    }
}

// Round 8
// 415.024 us; speedup vs baseline: 1.0227x; 1.0122x over previous
//
#include <hip/hip_runtime.h>
#include <cstdint>

// Zoom-aware MSA, MI355X/gfx950. Inputs fp32, output fp32.
// R12: (1) GEMMs back to R8's proven single-buffer GLDS loop (16KB LDS;
// R9/R11 dbuf experiments were null). (2) attn: XCD-aware block swizzle —
// the 8 qb-blocks sharing one (h,bl)'s K/V panels (256KB, L2-fits) now land
// on ONE XCD (was: 8 different XCDs) -> K/V L2-resident; plus T5 setprio
// around QK/PV MFMA clusters. (3) 4 weight-cvt launches merged into one.

#define SQ   1024
#define HID  1024
#define CEXP 0.18033688f      // (1/sqrt(64)) * log2(e)
#define LOG2E 1.44269504f

typedef __attribute__((ext_vector_type(8))) __bf16 bf16x8;
typedef __attribute__((ext_vector_type(8))) unsigned short ushort8;
typedef __attribute__((ext_vector_type(4))) float  floatx4;

__device__ __forceinline__ float b2f(unsigned short x) {
    return __builtin_bit_cast(float, (uint32_t)x << 16);
}
__device__ __forceinline__ unsigned short f2bf(float f) {
    uint32_t u = __builtin_bit_cast(uint32_t, f);
    u += 0x7fffu + ((u >> 16) & 1u);          // RTNE
    return (unsigned short)(u >> 16);
}

// async global->LDS, 16B per lane; LDS dest = wave-uniform base + lane*16.
__device__ __forceinline__ void glds16(const void* g, void* l) {
    __builtin_amdgcn_global_load_lds(
        (const __attribute__((address_space(1))) void*)g,
        (__attribute__((address_space(3))) void*)l, 16, 0, 0);
}

// fp32 -> bf16 elementwise with scale, n % 4 == 0.
__global__ void cvt(const float* __restrict__ s, unsigned short* __restrict__ d,
                    int n4, float scale) {
    const int i = blockIdx.x * blockDim.x + threadIdx.x;
    if (i >= n4) return;
    const floatx4 v = *(const floatx4*)(s + 4 * (size_t)i);
    uint32_t lo = (uint32_t)f2bf(v[0] * scale) | ((uint32_t)f2bf(v[1] * scale) << 16);
    uint32_t hi = (uint32_t)f2bf(v[2] * scale) | ((uint32_t)f2bf(v[3] * scale) << 16);
    ((uint2*)d)[i] = make_uint2(lo, hi);
}

// 3-tensor fp32 -> bf16 (q,k,v) in one launch; blockIdx.y selects tensor.
__global__ void cvt3(const float* __restrict__ s0, const float* __restrict__ s1,
                     const float* __restrict__ s2, unsigned short* __restrict__ d0,
                     unsigned short* __restrict__ d1, unsigned short* __restrict__ d2,
                     int n4) {
    const int i = blockIdx.x * blockDim.x + threadIdx.x;
    if (i >= n4) return;
    const int z = blockIdx.y;
    const float* s = z == 0 ? s0 : (z == 1 ? s1 : s2);
    unsigned short* d = z == 0 ? d0 : (z == 1 ? d1 : d2);
    const floatx4 v = *(const floatx4*)(s + 4 * (size_t)i);
    uint32_t lo = (uint32_t)f2bf(v[0]) | ((uint32_t)f2bf(v[1]) << 16);
    uint32_t hi = (uint32_t)f2bf(v[2]) | ((uint32_t)f2bf(v[3]) << 16);
    ((uint2*)d)[i] = make_uint2(lo, hi);
}

// 4 weight matrices fp32 -> bf16 in one launch; blockIdx.y selects.
__global__ void cvt4(const float* __restrict__ s0, const float* __restrict__ s1,
                     const float* __restrict__ s2, const float* __restrict__ s3,
                     unsigned short* __restrict__ d0, unsigned short* __restrict__ d1,
                     unsigned short* __restrict__ d2, unsigned short* __restrict__ d3,
                     int n4) {
    const int i = blockIdx.x * blockDim.x + threadIdx.x;
    if (i >= n4) return;
    const int z = blockIdx.y;
    const float* s = z == 0 ? s0 : (z == 1 ? s1 : (z == 2 ? s2 : s3));
    unsigned short* d = z == 0 ? d0 : (z == 1 ? d1 : (z == 2 ? d2 : d3));
    const floatx4 v = *(const floatx4*)(s + 4 * (size_t)i);
    uint32_t lo = (uint32_t)f2bf(v[0]) | ((uint32_t)f2bf(v[1]) << 16);
    uint32_t hi = (uint32_t)f2bf(v[2]) | ((uint32_t)f2bf(v[3]) << 16);
    ((uint2*)d)[i] = make_uint2(lo, hi);
}

// Fused Q/K/V projection: C_z = A_z[M,1024] @ W_z[1024,1024]^T + b_z.
// blockIdx.z picks (A,W,bias,C); z==2 (V) stores transposed
// [row>>10][n][row&1023]. R8-proven single-buffer GLDS loop, XCD swizzle.
__global__ __launch_bounds__(256) void gemm_qkv(
    const short* __restrict__ Aq, const short* __restrict__ Ak,
    const short* __restrict__ Av, const short* __restrict__ Wq_,
    const short* __restrict__ Wk_, const short* __restrict__ Wv_,
    const float* __restrict__ bq_, const float* __restrict__ bk_,
    const float* __restrict__ bv_, short* __restrict__ oq,
    short* __restrict__ ok, short* __restrict__ ov)
{
    __shared__ __align__(16) short As[4096];   // region r: rows 16r+c, k=quad*8
    __shared__ __align__(16) short Bs[4096];

    const int z = blockIdx.z;
    const short* A    = z == 0 ? Aq  : (z == 1 ? Ak  : Av);
    const short* Bw   = z == 0 ? Wq_ : (z == 1 ? Wk_ : Wv_);
    const float* bias = z == 0 ? bq_ : (z == 1 ? bk_ : bv_);
    short* C          = z == 0 ? oq  : (z == 1 ? ok  : ov);
    const bool trans  = (z == 2);

    const int tid = threadIdx.x;
    const int w = tid >> 6, lane = tid & 63;
    const int quad = lane >> 4, c = lane & 15;
    const int wr = w >> 1, wc = w & 1;

    // bijective XCD swizzle within the z-slice (nwg multiple of 8)
    const int nwg = gridDim.x * gridDim.y;
    const int id  = blockIdx.y * gridDim.x + blockIdx.x;
    const int nid = (id & 7) * (nwg >> 3) + (id >> 3);
    const int bn = nid & 7, bm = nid >> 3;

    const short* ag0 = A  + (size_t)(bm * 128 + w * 16 + c) * HID + quad * 8;
    const short* ag1 = ag0 + (size_t)64 * HID;
    const short* bg0 = Bw + (size_t)(bn * 128 + w * 16 + c) * HID + quad * 8;
    const short* bg1 = bg0 + (size_t)64 * HID;

    floatx4 acc[4][4] = {};

    for (int kt = 0; kt < 32; ++kt) {
        __syncthreads();
        glds16(ag0, As + w * 512);
        glds16(ag1, As + (w + 4) * 512);
        glds16(bg0, Bs + w * 512);
        glds16(bg1, Bs + (w + 4) * 512);
        asm volatile("s_waitcnt vmcnt(0)" ::: "memory");   // guarantee DMA landed
        __syncthreads();
        ag0 += 32; ag1 += 32; bg0 += 32; bg1 += 32;

        bf16x8 a[4], b[4];
#pragma unroll
        for (int i = 0; i < 4; ++i)
            a[i] = *(const bf16x8*)(As + (wr * 4 + i) * 512 + lane * 8);
#pragma unroll
        for (int j = 0; j < 4; ++j)
            b[j] = *(const bf16x8*)(Bs + (wc * 4 + j) * 512 + lane * 8);
#pragma unroll
        for (int i = 0; i < 4; ++i)
#pragma unroll
            for (int j = 0; j < 4; ++j)
                acc[i][j] = __builtin_amdgcn_mfma_f32_16x16x32_bf16(a[i], b[j], acc[i][j], 0, 0, 0);
    }

    float bsv[4];
#pragma unroll
    for (int j = 0; j < 4; ++j)
        bsv[j] = bias[bn * 128 + wc * 64 + j * 16 + c];

#pragma unroll
    for (int i = 0; i < 4; ++i) {
#pragma unroll
        for (int j = 0; j < 4; ++j) {
            const int n = bn * 128 + wc * 64 + j * 16 + c;
#pragma unroll
            for (int r = 0; r < 4; ++r) {
                const int row = bm * 128 + wr * 64 + i * 16 + quad * 4 + r;  // C/D: row=quad*4+reg, col=c
                const float val = acc[i][j][r] + bsv[j];
                const size_t idx = trans
                    ? ((size_t)(row >> 10) * HID + n) * SQ + (row & 1023)
                    : (size_t)row * HID + n;
                C[idx] = (short)f2bf(val);
            }
        }
    }
}

// O-projection: C = A[M,1024] @ Bw^T + bias, fp32 out. R8-proven loop.
__global__ __launch_bounds__(256) void gemm_bt(
    const short* __restrict__ A, const short* __restrict__ Bw,
    const float* __restrict__ bias, float* __restrict__ C, size_t cOff)
{
    __shared__ __align__(16) short As[4096];
    __shared__ __align__(16) short Bs[4096];

    const int tid = threadIdx.x;
    const int w = tid >> 6, lane = tid & 63;
    const int quad = lane >> 4, c = lane & 15;
    const int wr = w >> 1, wc = w & 1;

    const int nwg = gridDim.x * gridDim.y;
    const int id  = blockIdx.y * gridDim.x + blockIdx.x;
    const int nid = (id & 7) * (nwg >> 3) + (id >> 3);
    const int bn = nid & 7, bm = nid >> 3;

    const short* ag0 = A  + (size_t)(bm * 128 + w * 16 + c) * HID + quad * 8;
    const short* ag1 = ag0 + (size_t)64 * HID;
    const short* bg0 = Bw + (size_t)(bn * 128 + w * 16 + c) * HID + quad * 8;
    const short* bg1 = bg0 + (size_t)64 * HID;

    floatx4 acc[4][4] = {};

    for (int kt = 0; kt < 32; ++kt) {
        __syncthreads();
        glds16(ag0, As + w * 512);
        glds16(ag1, As + (w + 4) * 512);
        glds16(bg0, Bs + w * 512);
        glds16(bg1, Bs + (w + 4) * 512);
        asm volatile("s_waitcnt vmcnt(0)" ::: "memory");
        __syncthreads();
        ag0 += 32; ag1 += 32; bg0 += 32; bg1 += 32;

        bf16x8 a[4], b[4];
#pragma unroll
        for (int i = 0; i < 4; ++i)
            a[i] = *(const bf16x8*)(As + (wr * 4 + i) * 512 + lane * 8);
#pragma unroll
        for (int j = 0; j < 4; ++j)
            b[j] = *(const bf16x8*)(Bs + (wc * 4 + j) * 512 + lane * 8);
#pragma unroll
        for (int i = 0; i < 4; ++i)
#pragma unroll
            for (int j = 0; j < 4; ++j)
                acc[i][j] = __builtin_amdgcn_mfma_f32_16x16x32_bf16(a[i], b[j], acc[i][j], 0, 0, 0);
    }

    float bsv[4];
#pragma unroll
    for (int j = 0; j < 4; ++j)
        bsv[j] = bias[bn * 128 + wc * 64 + j * 16 + c];

#pragma unroll
    for (int i = 0; i < 4; ++i)
#pragma unroll
        for (int j = 0; j < 4; ++j) {
            const int n = bn * 128 + wc * 64 + j * 16 + c;
#pragma unroll
            for (int r = 0; r < 4; ++r) {
                const int row = bm * 128 + wr * 64 + i * 16 + quad * 4 + r;
                C[cOff + (size_t)row * HID + n] = acc[i][j][r] + bsv[j];
            }
        }
}

// Fused attention, 64-key tiles. Block = 128 q-rows of (bl, h); wave = 32
// q-rows. XCD swizzle: the 8 qb-blocks of one (h,bl) share an XCD (K/V
// panels = 256KB stay L2-local). T5 setprio around MFMA clusters. Bias
// dwords for tile kt+1 prefetched into regs during PV. exp2, prefolded log2e.
__global__ __launch_bounds__(256) void attn(
    const short* __restrict__ qh, const short* __restrict__ kh,
    const short* __restrict__ vht, const unsigned short* __restrict__ abc,
    const float* __restrict__ zbf, short* __restrict__ aout, int b0)
{
    __shared__ __align__(16) short Kf[4096];     // region sub*4+half*2+kb
    __shared__ __align__(16) short Vf[4096];     // region sub*4+dt
    __shared__ __align__(16) short Ps[4][2304];  // per-wave 32 x 72-stride
    __shared__ float Zs[1152];

    const int tid = threadIdx.x;
    const int w = tid >> 6, lane = tid & 63;
    const int quad = lane >> 4, c = lane & 15;

    // XCD swizzle (G==8 case: 1024 blocks). Blocks with equal (h,bl) get
    // equal linear%8 -> same XCD. Bijection: B -> (qb, hb=(B>>6)*8+(B&7)).
    int qb, h, bl;
    if (gridDim.z == 8) {
        const int B = blockIdx.x + (blockIdx.y << 3) + (blockIdx.z << 7);
        const int hb = (B >> 6) * 8 + (B & 7);
        qb = (B >> 3) & 7; h = hb & 15; bl = hb >> 4;
    } else {
        qb = blockIdx.x; h = blockIdx.y; bl = blockIdx.z;
    }
    const int b = b0 + bl;

    for (int j = tid; j < 1151; j += 256)
        Zs[j] = zbf[qb * 128 + j] * LOG2E;

    const size_t blS = (size_t)bl * SQ;

    bf16x8 qa[2][2];     // A-frag: A[m=lane&15][k=quad*8+j]
#pragma unroll
    for (int m = 0; m < 2; ++m)
#pragma unroll
        for (int half = 0; half < 2; ++half)
            qa[m][half] = *(const bf16x8*)(qh + (blS + qb * 128 + w * 32 + m * 16 + c) * HID
                                               + h * 64 + half * 32 + quad * 8);

    // wave w stages: K regions (sub,half=w>>1,kb=w&1), V regions (sub,dt=w)
    const short* kg = kh  + (blS + 2 * c + (w & 1)) * HID + h * 64 + (w >> 1) * 32 + quad * 8;
    const short* vg = vht + ((size_t)bl * HID + h * 64 + w * 16 + c) * SQ + quad * 8;
    const size_t bge = ((size_t)b * SQ + qb * 128 + w * 32 + quad * 4) * SQ;

    bf16x8 kv0 = *(const bf16x8*)kg, kv1 = *(const bf16x8*)(kg + 32 * HID);
    bf16x8 vv0 = *(const bf16x8*)vg, vv1 = *(const bf16x8*)(vg + 32);

    uint32_t bp[2][4][2];
    auto loadB = [&](int K0) {
#pragma unroll
        for (int m = 0; m < 2; ++m)
#pragma unroll
            for (int r = 0; r < 4; ++r)
#pragma unroll
                for (int sub = 0; sub < 2; ++sub)
                    bp[m][r][sub] = *(const uint32_t*)(abc + bge + (size_t)(m * 16 + r) * SQ
                                                        + K0 + sub * 32 + 2 * c);
    };
    loadB(0);

    floatx4 o[2][4] = {};
    float sume[2][4] = {};

    for (int kt = 0; kt < 16; ++kt) {
        __syncthreads();
        *(bf16x8*)(Kf + w * 512 + lane * 8)       = kv0;
        *(bf16x8*)(Kf + (w + 4) * 512 + lane * 8) = kv1;
        *(bf16x8*)(Vf + w * 512 + lane * 8)       = vv0;
        *(bf16x8*)(Vf + (w + 4) * 512 + lane * 8) = vv1;
        __syncthreads();

        if (kt < 15) {                            // prefetch next 64-key tile
            kg += 64 * HID; vg += 64;
            kv0 = *(const bf16x8*)kg; kv1 = *(const bf16x8*)(kg + 32 * HID);
            vv0 = *(const bf16x8*)vg; vv1 = *(const bf16x8*)(vg + 32);
        }

        floatx4 sc[2][2][2] = {};                 // [m][sub][kb]
        __builtin_amdgcn_s_setprio(1);
#pragma unroll
        for (int sub = 0; sub < 2; ++sub) {
            bf16x8 kf[2][2];
#pragma unroll
            for (int half = 0; half < 2; ++half)
#pragma unroll
                for (int kb = 0; kb < 2; ++kb)
                    kf[half][kb] = *(const bf16x8*)(Kf + (sub * 4 + half * 2 + kb) * 512 + lane * 8);
#pragma unroll
            for (int m = 0; m < 2; ++m)
#pragma unroll
                for (int kb = 0; kb < 2; ++kb) {
                    sc[m][sub][kb] = __builtin_amdgcn_mfma_f32_16x16x32_bf16(qa[m][0], kf[0][kb], sc[m][sub][kb], 0, 0, 0);
                    sc[m][sub][kb] = __builtin_amdgcn_mfma_f32_16x16x32_bf16(qa[m][1], kf[1][kb], sc[m][sub][kb], 0, 0, 0);
                }
        }
        __builtin_amdgcn_s_setprio(0);

        const int k0 = kt * 64;
#pragma unroll
        for (int m = 0; m < 2; ++m) {
#pragma unroll
            for (int r = 0; r < 4; ++r) {
                const int lrq = w * 32 + m * 16 + quad * 4 + r;
                const int tb = lrq + 1023 - k0;                   // Zs idx = tb - local key
#pragma unroll
                for (int sub = 0; sub < 2; ++sub) {
                    const int kl = sub * 32 + 2 * c;
                    const uint32_t bv_ = bp[m][r][sub];
                    const float z0 = Zs[tb - kl], z1 = Zs[tb - kl - 1];
                    const float s0 = sc[m][sub][0][r] * CEXP + z0 + b2f((unsigned short)(bv_ & 0xffffu));
                    const float s1 = sc[m][sub][1][r] * CEXP + z1
                                   + __builtin_bit_cast(float, bv_ & 0xffff0000u);
                    const float e0 = __builtin_amdgcn_exp2f(s0);
                    const float e1 = __builtin_amdgcn_exp2f(s1);
                    sume[m][r] += e0 + e1;
                    const uint32_t pp = (uint32_t)f2bf(e0) | ((uint32_t)f2bf(e1) << 16);
                    *(uint32_t*)(&Ps[w][0] + (m * 16 + quad * 4 + r) * 72 + kl) = pp;
                }
            }
        }

        if (kt < 15) loadB(k0 + 64);              // hide bias latency under PV

        __builtin_amdgcn_s_setprio(1);
#pragma unroll
        for (int sub = 0; sub < 2; ++sub) {
            bf16x8 ap[2];
#pragma unroll
            for (int m = 0; m < 2; ++m)
                ap[m] = *(const bf16x8*)(&Ps[w][0] + (m * 16 + c) * 72 + sub * 32 + quad * 8);
#pragma unroll
            for (int dt = 0; dt < 4; ++dt) {
                const bf16x8 vf = *(const bf16x8*)(Vf + (sub * 4 + dt) * 512 + lane * 8);
#pragma unroll
                for (int m = 0; m < 2; ++m)
                    o[m][dt] = __builtin_amdgcn_mfma_f32_16x16x32_bf16(ap[m], vf, o[m][dt], 0, 0, 0);
            }
        }
        __builtin_amdgcn_s_setprio(0);
    }

#pragma unroll
    for (int m = 0; m < 2; ++m)
#pragma unroll
        for (int r = 0; r < 4; ++r) {
            float s = sume[m][r];
            s += __shfl_xor(s, 1);
            s += __shfl_xor(s, 2);
            s += __shfl_xor(s, 4);
            s += __shfl_xor(s, 8);
            sume[m][r] = 1.0f / s;
        }

#pragma unroll
    for (int m = 0; m < 2; ++m)
#pragma unroll
        for (int dt = 0; dt < 4; ++dt)
#pragma unroll
            for (int r = 0; r < 4; ++r) {
                const size_t row = blS + qb * 128 + w * 32 + m * 16 + quad * 4 + r;
                ((unsigned short*)aout)[row * HID + h * 64 + dt * 16 + c] =
                    f2bf(o[m][dt][r] * sume[m][r]);
            }
}

extern "C" void kernel_launch(void* const* d_in, const int* in_sizes, int n_in,
                              void* d_out, int out_size, void* d_ws, size_t ws_size,
                              hipStream_t stream) {
    const float* q  = (const float*)d_in[0];
    const float* k  = (const float*)d_in[1];
    const float* v  = (const float*)d_in[2];
    const float* ab = (const float*)d_in[3];
    const float* Wq = (const float*)d_in[4];  const float* bq = (const float*)d_in[5];
    const float* Wk = (const float*)d_in[6];  const float* bk = (const float*)d_in[7];
    const float* Wv = (const float*)d_in[8];  const float* bv = (const float*)d_in[9];
    const float* Wo = (const float*)d_in[10]; const float* bo = (const float*)d_in[11];
    const float* zb = (const float*)d_in[12];

    const size_t perB = (size_t)SQ * HID;            // 1M elems per batch
    const size_t WN   = (size_t)HID * HID;           // 1M elems per weight

    // ws: 4 bf16 weights (8MB) + bf16 attn_bias (16MB) + 6 x G x 2MB
    // (cbq,cbk,cbv, qh,khp,vht; ao aliases cbq).
    int G = 8;
    while (G > 1 && 24ull * 1024 * 1024 + 12ull * G * perB > ws_size) G >>= 1;

    unsigned short* Wqc = (unsigned short*)d_ws;
    unsigned short* Wkc = Wqc + WN;
    unsigned short* Wvc = Wkc + WN;
    unsigned short* Woc = Wvc + WN;
    unsigned short* abc = Woc + WN;                  // 8M elems (all batches)
    short* cbq = (short*)(abc + 8 * perB);           // bf16 A staging (q,k,v)
    short* cbk = cbq + (size_t)G * perB;
    short* cbv = cbk + (size_t)G * perB;
    short* qh  = cbv + (size_t)G * perB;
    short* khp = qh  + (size_t)G * perB;
    short* vht = khp + (size_t)G * perB;
    short* ao  = cbq;                                // alias: cb* dead after QKV

    const dim3 bt(256);
    const int ngroups = 8 / G;
    const int cn4 = (int)(G * perB / 4);
    const int cgrid = (cn4 + 255) / 256;

    cvt4<<<dim3((WN / 4 + 255) / 256, 4), 256, 0, stream>>>(
        Wq, Wk, Wv, Wo, Wqc, Wkc, Wvc, Woc, (int)(WN / 4));
    cvt<<<(8 * perB / 4 + 255) / 256, 256, 0, stream>>>(ab, abc, 8 * perB / 4, LOG2E);

    for (int g = 0; g < ngroups; ++g) {
        const size_t off = (size_t)g * G * perB;
        cvt3<<<dim3(cgrid, 3), 256, 0, stream>>>(
            q + off, k + off, v + off,
            (unsigned short*)cbq, (unsigned short*)cbk, (unsigned short*)cbv, cn4);
        gemm_qkv<<<dim3(8, G * 8, 3), bt, 0, stream>>>(
            cbq, cbk, cbv, (short*)Wqc, (short*)Wkc, (short*)Wvc,
            bq, bk, bv, qh, khp, vht);
        attn<<<dim3(8, 16, G), bt, 0, stream>>>(qh, khp, vht, abc, zb, ao, g * G);
        gemm_bt<<<dim3(8, G * 8), bt, 0, stream>>>(ao, (short*)Woc, bo, (float*)d_out, off);
    }
}